// Round 7
// baseline (114.981 us; speedup 1.0000x reference)
//
#include <hip/hip_runtime.h>
#include <hip/hip_bf16.h>

#define BB 16
#define CC 64
#define NN 4096      // H*W
#define MM 1024      // pooled spatial
#define LOG2E 1.4426950408889634f

typedef unsigned short u16;
typedef unsigned int u32;
typedef __attribute__((ext_vector_type(8))) short bf16x8;
typedef __attribute__((ext_vector_type(4))) float f32x4;

__device__ inline u16 f2bf(float f) {
    union { float f; u32 u; } v; v.f = f;
    return (u16)((v.u + 0x7FFFu + ((v.u >> 16) & 1u)) >> 16);
}
__device__ inline bf16x8 ld_bf16x8(const u16* p) {
    union { uint4 u; bf16x8 b; } c; c.u = *(const uint4*)p; return c.b;
}
__device__ inline bf16x8 ld2_bf16x8(const u16* p0, const u16* p1) {
    union { uint2 u[2]; bf16x8 b; } c;
    c.u[0] = *(const uint2*)p0;
    c.u[1] = *(const uint2*)p1;
    return c.b;
}
__device__ inline u32 cvt_pk_bf16(float lo, float hi) {
    __hip_bfloat162 h = __float22bfloat162_rn(make_float2(lo, hi));
    return *(u32*)&h;
}

// workspace (u16): theta_b [B][N][8] (pre-scaled by log2e) : 524288
//                  phi_b [B][M][8] : 131072 | gT_b [B][32][M] : 524288

// ---------------------------------------------------------------------------
// Kernel 1: MFMA 1x1 convs + 2x2 maxpool -> bf16 theta(*log2e)/phi/gT.
// grid (32,16): block = 128 px (2 image rows = 1 pooled row) -> 2 blocks/CU.
// Wave w owns px cols w*16..+15 of both rows (r-tiles 0,1). Horizontal pool
// = shfl_xor(1); vertical pool = in-lane max across r-tiles. No LDS at all.
// Weights: 6 A-frags in registers. x: direct global dword loads -> B-frags.
// ---------------------------------------------------------------------------
__global__ __launch_bounds__(256) void prep_kernel(
    const float* __restrict__ x, const float* __restrict__ w_theta,
    const float* __restrict__ w_phi, const float* __restrict__ w_g,
    u16* __restrict__ theta_b, u16* __restrict__ phi_b, u16* __restrict__ gT_b)
{
    const int t = threadIdx.x, w = t >> 6, lane = t & 63;
    const int m16 = lane & 15, quad = lane >> 4;
    const int b = blockIdx.y, bx = blockIdx.x;
    const int nbase = bx * 128;

    // A-frags: A[m=out-ch][k=in-ch]; f0 = theta(m16<8)/phi(m16>=8), f1/f2 = g
    bf16x8 A[3][2];
    {
        const float* row0 = (m16 < 8) ? (w_theta + m16 * 64) : (w_phi + (m16 - 8) * 64);
        const float* rows[3] = { row0, w_g + m16 * 64, w_g + (16 + m16) * 64 };
        #pragma unroll
        for (int f = 0; f < 3; ++f) {
            #pragma unroll
            for (int kc = 0; kc < 2; ++kc) {
                const float* p = rows[f] + kc * 32 + quad * 8;
                const float4 f0 = *(const float4*)p;
                const float4 f1 = *(const float4*)(p + 4);
                union { u32 d[4]; bf16x8 v; } a;
                a.d[0] = cvt_pk_bf16(f0.x, f0.y);
                a.d[1] = cvt_pk_bf16(f0.z, f0.w);
                a.d[2] = cvt_pk_bf16(f1.x, f1.y);
                a.d[3] = cvt_pk_bf16(f1.z, f1.w);
                A[f][kc] = a.v;
            }
        }
    }

    const float* xb = x + (size_t)b * CC * NN;
    const f32x4 zero4 = {0.f, 0.f, 0.f, 0.f};
    f32x4 acc[2][3];
    #pragma unroll
    for (int r = 0; r < 2; ++r)
        #pragma unroll
        for (int f = 0; f < 3; ++f) acc[r][f] = zero4;

    #pragma unroll
    for (int r = 0; r < 2; ++r) {
        const int px = nbase + r * 64 + w * 16 + m16;
        #pragma unroll
        for (int kc = 0; kc < 2; ++kc) {
            float xv[8];
            #pragma unroll
            for (int j = 0; j < 8; ++j)
                xv[j] = xb[(size_t)(kc * 32 + quad * 8 + j) * NN + px];
            union { u32 d[4]; bf16x8 v; } bxf;
            bxf.d[0] = cvt_pk_bf16(xv[0], xv[1]);
            bxf.d[1] = cvt_pk_bf16(xv[2], xv[3]);
            bxf.d[2] = cvt_pk_bf16(xv[4], xv[5]);
            bxf.d[3] = cvt_pk_bf16(xv[6], xv[7]);
            #pragma unroll
            for (int f = 0; f < 3; ++f)
                acc[r][f] = __builtin_amdgcn_mfma_f32_16x16x32_bf16(A[f][kc], bxf.v, acc[r][f], 0, 0, 0);
        }
    }

    // theta (frag0 quads 0,1; ch = quad*4+rr), pre-scaled by log2e
    if (quad < 2) {
        #pragma unroll
        for (int r = 0; r < 2; ++r) {
            const int px = nbase + r * 64 + w * 16 + m16;
            uint2 v;
            v.x = cvt_pk_bf16(acc[r][0][0] * LOG2E, acc[r][0][1] * LOG2E);
            v.y = cvt_pk_bf16(acc[r][0][2] * LOG2E, acc[r][0][3] * LOG2E);
            *(uint2*)(theta_b + ((size_t)b * NN + px) * 8 + quad * 4) = v;
        }
    }

    // pooling: horizontal shfl, vertical in-lane (rows r=0,1)
    float pv[3][4];
    #pragma unroll
    for (int f = 0; f < 3; ++f)
        #pragma unroll
        for (int rr = 0; rr < 4; ++rr) {
            float h0 = acc[0][f][rr]; h0 = fmaxf(h0, __shfl_xor(h0, 1, 64));
            float h1 = acc[1][f][rr]; h1 = fmaxf(h1, __shfl_xor(h1, 1, 64));
            pv[f][rr] = fmaxf(h0, h1);
        }

    if ((m16 & 1) == 0) {
        const int pcol = w * 8 + (m16 >> 1);
        const int m = bx * 32 + pcol;             // pooled row = bx
        if (quad >= 2) {   // phi ch = (quad-2)*4 + rr
            uint2 v;
            v.x = cvt_pk_bf16(pv[0][0], pv[0][1]);
            v.y = cvt_pk_bf16(pv[0][2], pv[0][3]);
            *(uint2*)(phi_b + ((size_t)b * MM + m) * 8 + (quad - 2) * 4) = v;
        }
        #pragma unroll
        for (int f = 1; f < 3; ++f)
            #pragma unroll
            for (int rr = 0; rr < 4; ++rr) {
                const int d = (f - 1) * 16 + quad * 4 + rr;
                gT_b[(size_t)b * 32 * MM + (size_t)d * MM + m] = f2bf(pv[f][rr]);
            }
    }
}

// ---------------------------------------------------------------------------
// Kernel 2: fused attention + output conv + residual.
// grid (32,16), 256 threads = 4 waves; wave w owns 32 queries (2 q-tiles) ->
// phi/g LDS reads amortized 2x across q-tiles. theta pre-scaled by log2e so
// softmax numerator is exp2(S) (native v_exp_f32, no mul). 2 blocks/CU.
// ---------------------------------------------------------------------------
__global__ __launch_bounds__(256, 2) void attn_out_kernel(
    const u16* __restrict__ theta_b, const u16* __restrict__ phi_b,
    const u16* __restrict__ gT_b, const float* __restrict__ w_o,
    const float* __restrict__ x, const float* __restrict__ gamma_p,
    float* __restrict__ out)
{
    __shared__ u16 phis[1024 * 8];   // 16 KB, whole batch of keys
    __shared__ u16 gs[32 * 264];     // [d][256 keys + pad8], 16.5 KB
    __shared__ u16 oS[128 * 40];     // [q_local][d + pad8], 10 KB

    const int t = threadIdx.x, w = t >> 6, lane = t & 63;
    const int m16 = lane & 15, quad = lane >> 4;
    const int b = blockIdx.y, qbase = blockIdx.x * 128;

    const u16* phg = phi_b + (size_t)b * MM * 8;
    const u16* gtg = gT_b + (size_t)b * 32 * MM;

    #pragma unroll
    for (int i = 0; i < 4; ++i)
        ((uint4*)phis)[i * 256 + t] = ((const uint4*)phg)[i * 256 + t];

    // 2 persistent theta B-frags (quad0 real): q = qbase + w*32 + u*16 + m16
    bf16x8 thB[2] = {{0,0,0,0,0,0,0,0}, {0,0,0,0,0,0,0,0}};
    if (quad == 0) {
        #pragma unroll
        for (int u = 0; u < 2; ++u)
            thB[u] = ld_bf16x8(theta_b + ((size_t)b * NN + qbase + w * 32 + u * 16 + m16) * 8);
    }

    bf16x8 woA[4];
    #pragma unroll
    for (int cf = 0; cf < 4; ++cf) {
        const float* wp = w_o + (cf * 16 + m16) * 32 + quad * 8;
        const float4 f0 = *(const float4*)wp;
        const float4 f1 = *(const float4*)(wp + 4);
        union { u32 d[4]; bf16x8 v; } a;
        a.d[0] = cvt_pk_bf16(f0.x, f0.y);
        a.d[1] = cvt_pk_bf16(f0.z, f0.w);
        a.d[2] = cvt_pk_bf16(f1.x, f1.y);
        a.d[3] = cvt_pk_bf16(f1.z, f1.w);
        woA[cf] = a.v;
    }

    bf16x8 onesA;
    #pragma unroll
    for (int i = 0; i < 8; ++i) onesA[i] = (short)0x3F80;

    const f32x4 zero4 = {0.f, 0.f, 0.f, 0.f};
    f32x4 oT0[2] = {zero4, zero4}, oT1[2] = {zero4, zero4}, lacc[2] = {zero4, zero4};

    uint4 r[4];
    #pragma unroll
    for (int i = 0; i < 4; ++i) {
        const int f = i * 256 + t, d = f >> 5, ku = f & 31;
        r[i] = *(const uint4*)(gtg + (size_t)d * MM + ku * 8);
    }

    for (int c = 0; c < 4; ++c) {
        __syncthreads();
        #pragma unroll
        for (int i = 0; i < 4; ++i) {
            const int f = i * 256 + t, d = f >> 5, ku = f & 31;
            *(uint4*)(gs + d * 264 + ku * 8) = r[i];
        }
        __syncthreads();
        if (c < 3) {
            #pragma unroll
            for (int i = 0; i < 4; ++i) {
                const int f = i * 256 + t, d = f >> 5, ku = f & 31;
                r[i] = *(const uint4*)(gtg + (size_t)d * MM + (c + 1) * 256 + ku * 8);
            }
        }

        #pragma unroll
        for (int kblk = 0; kblk < 8; ++kblk) {
            const int kb = c * 256 + kblk * 32;
            bf16x8 phA0 = {0, 0, 0, 0, 0, 0, 0, 0};
            bf16x8 phA1 = {0, 0, 0, 0, 0, 0, 0, 0};
            if (quad == 0) {
                phA0 = ld_bf16x8(phis + (size_t)(kb + m16) * 8);
                phA1 = ld_bf16x8(phis + (size_t)(kb + 16 + m16) * 8);
            }
            // g A-frags shared by both q-tiles (key-permuted slot order)
            const u16* g0p = gs + m16 * 264 + kblk * 32 + quad * 4;
            const u16* g1p = gs + (16 + m16) * 264 + kblk * 32 + quad * 4;
            const bf16x8 gA0 = ld2_bf16x8(g0p, g0p + 16);
            const bf16x8 gA1 = ld2_bf16x8(g1p, g1p + 16);

            #pragma unroll
            for (int u = 0; u < 2; ++u) {
                const f32x4 Sa = __builtin_amdgcn_mfma_f32_16x16x32_bf16(phA0, thB[u], zero4, 0, 0, 0);
                const f32x4 Sb = __builtin_amdgcn_mfma_f32_16x16x32_bf16(phA1, thB[u], zero4, 0, 0, 0);

                union { u32 d[4]; bf16x8 v; } pb;
                pb.d[0] = cvt_pk_bf16(exp2f(Sa[0]), exp2f(Sa[1]));
                pb.d[1] = cvt_pk_bf16(exp2f(Sa[2]), exp2f(Sa[3]));
                pb.d[2] = cvt_pk_bf16(exp2f(Sb[0]), exp2f(Sb[1]));
                pb.d[3] = cvt_pk_bf16(exp2f(Sb[2]), exp2f(Sb[3]));

                oT0[u]  = __builtin_amdgcn_mfma_f32_16x16x32_bf16(gA0, pb.v, oT0[u], 0, 0, 0);
                oT1[u]  = __builtin_amdgcn_mfma_f32_16x16x32_bf16(gA1, pb.v, oT1[u], 0, 0, 0);
                lacc[u] = __builtin_amdgcn_mfma_f32_16x16x32_bf16(onesA, pb.v, lacc[u], 0, 0, 0);
            }
        }
    }

    // normalize in-lane; transpose via oS (wave reads only its own rows)
    #pragma unroll
    for (int u = 0; u < 2; ++u) {
        const float inv = 1.0f / lacc[u][0];
        u16* orow = oS + (size_t)(w * 32 + u * 16 + m16) * 40;
        uint2 a, b2;
        a.x  = cvt_pk_bf16(oT0[u][0] * inv, oT0[u][1] * inv);
        a.y  = cvt_pk_bf16(oT0[u][2] * inv, oT0[u][3] * inv);
        b2.x = cvt_pk_bf16(oT1[u][0] * inv, oT1[u][1] * inv);
        b2.y = cvt_pk_bf16(oT1[u][2] * inv, oT1[u][3] * inv);
        *(uint2*)(orow + quad * 4) = a;
        *(uint2*)(orow + 16 + quad * 4) = b2;
    }
    __syncthreads();

    // output conv: D[m=c][n=px] = w_o @ o; out = gamma*D + x
    const float gamma = *gamma_p;
    #pragma unroll
    for (int u = 0; u < 2; ++u) {
        const bf16x8 oB = ld_bf16x8(oS + (size_t)(w * 32 + u * 16 + m16) * 40 + quad * 8);
        #pragma unroll
        for (int cf = 0; cf < 4; ++cf) {
            const f32x4 D = __builtin_amdgcn_mfma_f32_16x16x32_bf16(woA[cf], oB, zero4, 0, 0, 0);
            #pragma unroll
            for (int rr = 0; rr < 4; ++rr) {
                const int cch = cf * 16 + quad * 4 + rr;
                const size_t adr = ((size_t)b * CC + cch) * NN + qbase + w * 32 + u * 16 + m16;
                out[adr] = gamma * D[rr] + x[adr];
            }
        }
    }
}

// ---------------------------------------------------------------------------
extern "C" void kernel_launch(void* const* d_in, const int* in_sizes, int n_in,
                              void* d_out, int out_size, void* d_ws, size_t ws_size,
                              hipStream_t stream) {
    const float* x       = (const float*)d_in[0];
    const float* w_theta = (const float*)d_in[1];
    const float* w_phi   = (const float*)d_in[2];
    const float* w_g     = (const float*)d_in[3];
    const float* w_o     = (const float*)d_in[4];
    const float* gamma   = (const float*)d_in[5];

    u16* theta_b = (u16*)d_ws;                      // 524288
    u16* phi_b   = theta_b + 524288;                // 131072
    u16* gT_b    = phi_b + 131072;                  // 524288
    float* out   = (float*)d_out;

    prep_kernel<<<dim3(32, 16), 256, 0, stream>>>(x, w_theta, w_phi, w_g,
                                                  theta_b, phi_b, gT_b);
    attn_out_kernel<<<dim3(32, 16), 256, 0, stream>>>(theta_b, phi_b, gT_b,
                                                      w_o, x, gamma, out);
}